// Round 2
// baseline (5252.481 us; speedup 1.0000x reference)
//
#include <hip/hip_runtime.h>
#include <hip/hip_fp16.h>
#include <math.h>

#define B_ 64
#define T_ 700
#define U_ 400
#define NF 704                        // flag slots per array (>= T_ + DEPTH)
#define FR_LS 13312                   // dwords per (layer,slot): 4 bt x 13 kc x 256

typedef _Float16 half8 __attribute__((ext_vector_type(8)));
typedef float float4v __attribute__((ext_vector_type(4)));

union AFrag { unsigned u[4]; half8 h; };

// ---- agent-scope (cross-XCD coherent) helpers ----
__device__ __forceinline__ unsigned agloadu(const unsigned* p) {
    return __hip_atomic_load(p, __ATOMIC_RELAXED, __HIP_MEMORY_SCOPE_AGENT);
}
__device__ __forceinline__ void agstoreu(unsigned* p, unsigned v) {
    __hip_atomic_store(p, v, __ATOMIC_RELAXED, __HIP_MEMORY_SCOPE_AGENT);
}
__device__ __forceinline__ float sig_(float v) {
    return __builtin_amdgcn_rcpf(1.f + __expf(-v));
}
__device__ __forceinline__ float tanh_(float v) {
    return 1.f - 2.f * __builtin_amdgcn_rcpf(__expf(2.f * v) + 1.f);
}
__device__ __forceinline__ void waitflag(const unsigned* f, unsigned target) {
    while (agloadu(f) < target) __builtin_amdgcn_s_sleep(2);
}
__device__ __forceinline__ unsigned f16u(float v) {
    union { _Float16 f; unsigned short s; } cv; cv.f = (_Float16)v; return (unsigned)cv.s;
}

// R9: cheap 1-dword/lane probe (sleep-backed, no correctness role) gates a
// batched pend-masked verify. The probe keeps the SPIN off the L3/VALU
// critical path (R8 post-mortem: batched-spin retries cost 52-104 loads each
// and regressed 67%); the verify is authoritative. Wrap-parity is ABA-safe:
// lagged consumption flags guarantee a slot only transitions (~p -> p) while
// being polled for parity p. EVERY dword in a region (incl. K-pad) is
// rewritten each step — see pad writer.
__device__ __forceinline__ void pollfrag13(const unsigned* __restrict__ base,
                                           const unsigned par,
                                           AFrag* __restrict__ a, const int lane)
{
    {   // probe: 1 dword/lane spread across all 13 chunks
        const unsigned* pp = base + (lane % 13) * 256 + ((lane * 37) & 255);
        while (!__all((int)(((agloadu(pp) ^ par) & 1u) == 0u)))
            __builtin_amdgcn_s_sleep(2);
    }
    unsigned pend = 0x1FFFu;
    do {
#pragma unroll
        for (int ck = 0; ck < 13; ++ck) if ((pend >> ck) & 1) {
#pragma unroll
            for (int d = 0; d < 4; ++d)
                a[ck].u[d] = agloadu(base + ck * 256 + d * 64 + lane);
        }
#pragma unroll
        for (int ck = 0; ck < 13; ++ck) if ((pend >> ck) & 1) {
            const unsigned m = (a[ck].u[0] ^ par) | (a[ck].u[1] ^ par)
                             | (a[ck].u[2] ^ par) | (a[ck].u[3] ^ par);
            if (__all((int)((m & 1u) == 0u))) pend &= ~(1u << ck);
        }
        if (pend) __builtin_amdgcn_s_sleep(3);
    } while (pend);
}

// Joint edge poll: lanes 0..31 probe the input region (parity parI), lanes
// 32..63 probe the own region (parity parO) — both detection latencies
// overlap in ONE cheap spin. Then a single interleaved 26-chunk verify
// (normally one iteration, since the probe already confirmed readiness).
__device__ __forceinline__ void pollfrag26(const unsigned* __restrict__ bI, const unsigned parI,
                                           const unsigned* __restrict__ bO, const unsigned parO,
                                           AFrag* __restrict__ aI, AFrag* __restrict__ aO,
                                           const int lane)
{
    {   // joint probe
        const unsigned* pp = ((lane < 32) ? bI : bO)
                           + ((lane & 31) % 13) * 256 + ((lane * 37) & 255);
        const unsigned pr = (lane < 32) ? parI : parO;
        while (!__all((int)(((agloadu(pp) ^ pr) & 1u) == 0u)))
            __builtin_amdgcn_s_sleep(2);
    }
    unsigned pend = 0x03FFFFFFu;
    do {
#pragma unroll
        for (int ck = 0; ck < 13; ++ck) if ((pend >> ck) & 1) {
#pragma unroll
            for (int d = 0; d < 4; ++d)
                aI[ck].u[d] = agloadu(bI + ck * 256 + d * 64 + lane);
        }
#pragma unroll
        for (int ck = 0; ck < 13; ++ck) if ((pend >> (13 + ck)) & 1) {
#pragma unroll
            for (int d = 0; d < 4; ++d)
                aO[ck].u[d] = agloadu(bO + ck * 256 + d * 64 + lane);
        }
#pragma unroll
        for (int ck = 0; ck < 13; ++ck) if ((pend >> ck) & 1) {
            const unsigned m = (aI[ck].u[0] ^ parI) | (aI[ck].u[1] ^ parI)
                             | (aI[ck].u[2] ^ parI) | (aI[ck].u[3] ^ parI);
            if (__all((int)((m & 1u) == 0u))) pend &= ~(1u << ck);
        }
#pragma unroll
        for (int ck = 0; ck < 13; ++ck) if ((pend >> (13 + ck)) & 1) {
            const unsigned m = (aO[ck].u[0] ^ parO) | (aO[ck].u[1] ^ parO)
                             | (aO[ck].u[2] ^ parO) | (aO[ck].u[3] ^ parO);
            if (__all((int)((m & 1u) == 0u))) pend &= ~(1u << (13 + ck));
        }
        if (pend) __builtin_amdgcn_s_sleep(3);
    } while (pend);
}

//  blocks 0..49   : layer 0, 8 units (32 gate-cols), A = h0[t-1]
//  blocks 50..149 : layer 1, 4 units, A = [h0[t] ; h1[t-1]]
//  blocks 150..249: layer 2, 4 units, A = [h1[t] ; h2[t-1]]
//  block 250      : output projection h2[t] @ Wd + bd
//  R9 sync scheme (= R8 protocol + R7 cheap detection):
//   - ALL data edges (own AND cross-layer) are parity-tagged data polls,
//     each gated by a 1-dword probe spin (cheap detector).
//   - Flags F1/F2/FO survive only as lagged CONSUMPTION markers
//     (anti-overwrite); F0 unused. Publishes sit right after the post-MFMA
//     barrier (loads already returned -> no release ordering needed).
//   - No per-step vmcnt(0) drain, no second __syncthreads.
//  blk 49/149/249 rewrite the 512 K-pad dwords (u=400..415) of their layer's
//  write slot every step — parity-correct, non-NaN.
template<int DEPTH, int CP>
__global__ void __launch_bounds__(256, 1)
lstm_mix(const float* __restrict__ x,
         const float* __restrict__ Wx0,
         const float* __restrict__ Wx1,
         const float* __restrict__ Wx2,
         const float* __restrict__ Wh,
         const float* __restrict__ bias,
         const float* __restrict__ pi,
         const float* __restrict__ pf,
         const float* __restrict__ po,
         const float* __restrict__ Wd,
         const float* __restrict__ bd,
         float* __restrict__ out,
         unsigned* __restrict__ ws)
{
    __shared__ alignas(16) _Float16 wlds[26 * 512];   // 26.6 KB B-frags [ck][lane][8]
    __shared__ alignas(16) float zlds[4 * 528];       // 8.4 KB per-wave z tiles
    __shared__ float gc[160];                          // gate constants

    const int LW = NF * CP * 32;
    unsigned* F0 = ws;
    unsigned* F1 = F0 + LW;
    unsigned* F2 = F1 + LW;
    unsigned* FO = F2 + LW;
    unsigned* frag0 = ws + (size_t)4 * LW;   // [3][DEPTH][FR_LS], init 0xFF (parity 1)

    const int blk  = blockIdx.x;
    const int tid  = threadIdx.x;
    const int lane = tid & 63;
    const int wv   = tid >> 6;
    const int cpi  = (blk + wv) & (CP - 1);

    int layer, u0;
    if      (blk < 50)  { layer = 0; u0 = blk * 8; }
    else if (blk < 150) { layer = 1; u0 = (blk - 50) * 4; }
    else if (blk < 250) { layer = 2; u0 = (blk - 150) * 4; }
    else                { layer = 3; u0 = 0; }

    const bool padw = (blk == 49) || (blk == 149) || (blk == 249);
    // pad dword addresses (2 per thread): kc=12, q in {2,3}, d in 0..3, b_loc 0..15
    int pad_off[2];
    {
        const int i0 = tid, i1 = tid + 256;
        pad_off[0] = (i0 >> 7) * 3328 + 12 * 256 + (((i0 >> 4) & 3) * 64)
                   + (2 + ((i0 >> 6) & 1)) * 16 + (i0 & 15);
        pad_off[1] = (i1 >> 7) * 3328 + 12 * 256 + (((i1 >> 4) & 3) * 64)
                   + (2 + ((i1 >> 6) & 1)) * 16 + (i1 & 15);
    }

    // ---- one-time: stage weights into LDS in B-fragment order ----
    {
        const float* __restrict__ Wxl = (layer == 1) ? Wx1 : Wx2;
        for (int i = tid; i < 26 * 64; i += 256) {
            const int ln = i & 63, ck = i >> 6;
            const int q = ln >> 4, nn = ln & 15;
            float vals[8];
#pragma unroll
            for (int j = 0; j < 8; ++j) {
                const int kc = ck % 13;
                const int k = kc * 32 + q * 8 + j;
                float v = 0.f;
                if (k < 400) {
                    if (layer == 0) {
                        const int col32 = (ck / 13) * 16 + nn;
                        const int gcol = (col32 >> 3) * U_ + u0 + (col32 & 7);
                        v = Wh[(size_t)k * 1600 + gcol];
                    } else if (layer < 3) {
                        const int gcol = (nn >> 2) * U_ + u0 + (nn & 3);
                        v = (ck >= 13) ? Wh[((size_t)layer * U_ + k) * 1600 + gcol]
                                       : Wxl[(size_t)k * 1600 + gcol];
                    } else {
                        if (ck < 13 && nn < 3) v = Wd[k * 3 + nn];
                    }
                }
                vals[j] = v;
            }
#pragma unroll
            for (int j = 0; j < 8; ++j)
                wlds[ck * 512 + ln * 8 + j] = (_Float16)vals[j];
        }
        if (layer == 0) {
            if (tid < 128) {
                const int col32 = tid >> 2, comp = tid & 3;
                const int gcol = (col32 >> 3) * U_ + u0 + (col32 & 7);
                gc[tid] = (comp == 0) ? bias[gcol] : Wx0[(size_t)(comp - 1) * 1600 + gcol];
            } else if (tid < 152) {
                const int idx = tid - 128, ul = idx / 3, j = idx - ul * 3;
                const float* pp = (j == 0) ? pi : (j == 1) ? pf : po;
                gc[tid] = pp[u0 + ul];
            }
        } else if (layer < 3) {
            if (tid < 16) {
                gc[tid] = bias[layer * 1600 + (tid >> 2) * U_ + u0 + (tid & 3)];
            } else if (tid < 28) {
                const int idx = tid - 16, ul = idx / 3, j = idx - ul * 3;
                const float* pp = (j == 0) ? pi : (j == 1) ? pf : po;
                gc[tid] = pp[layer * U_ + u0 + ul];
            }
        } else {
            if (tid < 3) gc[tid] = bd[tid];
        }
    }
    __syncthreads();

    const int wvz   = wv * 528;
    const int b_loc = lane & 15;
    const int quad  = lane >> 4;
    float cst[2] = {0.f, 0.f};

    for (int t = 0; t < T_; ++t) {
        const int sw = t % DEPTH;
        const int sr = (t + DEPTH - 1) % DEPTH;
        const unsigned pI = (unsigned)((t / DEPTH) & 1);          // parity written at t
        const unsigned pO = (unsigned)(((t - 1) / DEPTH) & 1);    // parity of h[t-1] slot

        // x prefetch (L0), independent of sync
        float x0, x1, x2;
        if (layer == 0) {
            const size_t xb = (size_t)(wv * 16 + b_loc) * T_ + t;
            x0 = x[xb * 3 + 0]; x1 = x[xb * 3 + 1]; x2 = x[xb * 3 + 2];
        }

        // ---- lagged anti-overwrite waits only (consumption markers) ----
        if (lane == 0 && wv == 0 && t >= DEPTH) {
            if      (layer == 0) waitflag(F1 + ((t - DEPTH) * CP + cpi) * 32, 100);
            else if (layer == 1) waitflag(F2 + ((t - DEPTH) * CP + cpi) * 32, 100);
            else if (layer == 2) waitflag(FO + ((t - DEPTH) * CP + cpi) * 32, 1);
        }
        asm volatile("" ::: "memory");

        // ---- data edges: probe-gated parity polls ----
        AFrag ainp[13];
        AFrag aown[13];
        if (layer == 0) {
            if (t >= 1) {
                const unsigned* frO = frag0 + (size_t)(0 * DEPTH + sr) * FR_LS + wv * 3328;
                pollfrag13(frO, pO, aown, lane);
            } else {
#pragma unroll
                for (int kc = 0; kc < 13; ++kc)
#pragma unroll
                    for (int d = 0; d < 4; ++d) aown[kc].u[d] = 0u;
            }
        } else if (layer < 3) {
            const unsigned* frI = frag0 + (size_t)((layer - 1) * DEPTH + sw) * FR_LS + wv * 3328;
            if (t >= 1) {
                const unsigned* frO = frag0 + (size_t)(layer * DEPTH + sr) * FR_LS + wv * 3328;
                pollfrag26(frI, pI, frO, pO, ainp, aown, lane);
            } else {
                pollfrag13(frI, pI, ainp, lane);
#pragma unroll
                for (int kc = 0; kc < 13; ++kc)
#pragma unroll
                    for (int d = 0; d < 4; ++d) aown[kc].u[d] = 0u;
            }
        } else {
            const unsigned* frI = frag0 + (size_t)(2 * DEPTH + sw) * FR_LS + wv * 3328;
            pollfrag13(frI, pI, aown, lane);
        }
        asm volatile("" ::: "memory");

        // ---- MFMA (accumulation order unchanged — preserves numerics) ----
        if (layer == 0) {
            float4v acc0 = {0.f, 0.f, 0.f, 0.f}, acc1 = {0.f, 0.f, 0.f, 0.f};
#pragma unroll
            for (int kc = 0; kc < 13; ++kc) {
                const half8 w0 = *(const half8*)&wlds[kc * 512 + lane * 8];
                const half8 w1 = *(const half8*)&wlds[(13 + kc) * 512 + lane * 8];
                acc0 = __builtin_amdgcn_mfma_f32_16x16x32_f16(aown[kc].h, w0, acc0, 0, 0, 0);
                acc1 = __builtin_amdgcn_mfma_f32_16x16x32_f16(aown[kc].h, w1, acc1, 0, 0, 0);
            }
#pragma unroll
            for (int r = 0; r < 4; ++r) {
                zlds[wvz + (quad * 4 + r) * 33 + b_loc] = acc0[r];
                zlds[wvz + (quad * 4 + r) * 33 + 16 + b_loc] = acc1[r];
            }
        } else if (layer < 3) {
            float4v acc = {0.f, 0.f, 0.f, 0.f};
#pragma unroll
            for (int kc = 0; kc < 13; ++kc) {
                const half8 wA = *(const half8*)&wlds[kc * 512 + lane * 8];          // Wx part
                const half8 wB = *(const half8*)&wlds[(13 + kc) * 512 + lane * 8];   // Wh part
                acc = __builtin_amdgcn_mfma_f32_16x16x32_f16(ainp[kc].h, wA, acc, 0, 0, 0);
                acc = __builtin_amdgcn_mfma_f32_16x16x32_f16(aown[kc].h, wB, acc, 0, 0, 0);
            }
#pragma unroll
            for (int r = 0; r < 4; ++r)
                zlds[wvz + (quad * 4 + r) * 33 + b_loc] = acc[r];
        } else {
            float4v acc = {0.f, 0.f, 0.f, 0.f};
#pragma unroll
            for (int kc = 0; kc < 13; ++kc) {
                const half8 w0 = *(const half8*)&wlds[kc * 512 + lane * 8];
                acc = __builtin_amdgcn_mfma_f32_16x16x32_f16(aown[kc].h, w0, acc, 0, 0, 0);
            }
            if (b_loc < 3) {
#pragma unroll
                for (int r = 0; r < 4; ++r)
                    out[((size_t)(wv * 16 + quad * 4 + r) * T_ + t) * 3 + b_loc] = acc[r] + gc[b_loc];
            }
        }
        __syncthreads();   // orders lagged wait before stores; all waves' loads consumed

        // ---- K-pad rewrite (designated block per layer): parity-correct, non-NaN ----
        if (padw) {
            unsigned* fr_dst = frag0 + (size_t)(layer * DEPTH + sw) * FR_LS;
            agstoreu(fr_dst + pad_off[0], pI);
            agstoreu(fr_dst + pad_off[1], pI);
        }

        // ---- consumption-marker publish (no release ordering needed:
        //      all input loads returned before the barrier above) ----
        if (layer != 0 && tid < CP) {
            unsigned* f = (layer == 1) ? F1 : (layer == 2) ? F2 : FO;
            __hip_atomic_fetch_add(f + (t * CP + tid) * 32, 1u,
                                   __ATOMIC_RELAXED, __HIP_MEMORY_SCOPE_AGENT);
        }

        // ---- gates (fp32) + parity-tagged h store in A-fragment layout ----
        if (layer == 0) {
            unsigned* fr_dst = frag0 + (size_t)(0 * DEPTH + sw) * FR_LS + wv * 3328;
#pragma unroll
            for (int q = 0; q < 2; ++q) {
                const int ul = q * 4 + quad;
                const int ug = u0 + ul;
                float z[4];
#pragma unroll
                for (int g = 0; g < 4; ++g) {
                    const int gb = (g * 8 + ul) * 4;
                    z[g] = zlds[wvz + b_loc * 33 + g * 8 + ul]
                         + gc[gb + 0] + x0 * gc[gb + 1] + x1 * gc[gb + 2] + x2 * gc[gb + 3];
                }
                const float cp = cst[q];
                const float ig = sig_(z[0] + gc[128 + ul * 3 + 0] * cp);
                const float fg = sig_(z[1] + gc[128 + ul * 3 + 1] * cp);
                const float cn = fg * cp + ig * tanh_(z[2]);
                const float og = sig_(z[3] + gc[128 + ul * 3 + 2] * cn);
                cst[q] = cn;
                const float hv = og * tanh_(cn);
                const float pv = __shfl_xor(hv, 16, 64);
                if ((quad & 1) == 0) {
                    const unsigned pw_ = ((f16u(hv) & ~1u) | pI) | (f16u(pv) << 16);
                    const int u = ug;                    // even
                    agstoreu(fr_dst + (u >> 5) * 256 + ((u & 7) >> 1) * 64
                                    + ((u >> 3) & 3) * 16 + b_loc, pw_);
                }
            }
        } else if (layer < 3) {
            unsigned* fr_dst = frag0 + (size_t)(layer * DEPTH + sw) * FR_LS + wv * 3328;
            const int ul = quad;
            float z[4];
#pragma unroll
            for (int g = 0; g < 4; ++g)
                z[g] = zlds[wvz + b_loc * 33 + g * 4 + ul] + gc[g * 4 + ul];
            const float cp = cst[0];
            const float ig = sig_(z[0] + gc[16 + ul * 3 + 0] * cp);
            const float fg = sig_(z[1] + gc[16 + ul * 3 + 1] * cp);
            const float cn = fg * cp + ig * tanh_(z[2]);
            const float og = sig_(z[3] + gc[16 + ul * 3 + 2] * cn);
            cst[0] = cn;
            const float hv = og * tanh_(cn);
            const float pv = __shfl_xor(hv, 16, 64);
            if ((ul & 1) == 0) {
                const unsigned pw_ = ((f16u(hv) & ~1u) | pI) | (f16u(pv) << 16);
                const int u = u0 + ul;                   // even
                agstoreu(fr_dst + (u >> 5) * 256 + ((u & 7) >> 1) * 64
                                + ((u >> 3) & 3) * 16 + b_loc, pw_);
            }
        }
        // no vmcnt(0), no second barrier: consumers verify data by parity,
        // and the next poll is self-gated by peers' stores.
    }
}

template<int DEPTH, int CP>
static void launch_variant(void* const* d_in, float* out, unsigned* ws, hipStream_t stream) {
    const float* x    = (const float*)d_in[0];
    const float* Wx0  = (const float*)d_in[1];
    const float* Wx1  = (const float*)d_in[2];
    const float* Wx2  = (const float*)d_in[3];
    const float* Wh   = (const float*)d_in[4];
    const float* bias = (const float*)d_in[5];
    const float* pi   = (const float*)d_in[6];
    const float* pf   = (const float*)d_in[7];
    const float* po   = (const float*)d_in[8];
    const float* Wd   = (const float*)d_in[9];
    const float* bd   = (const float*)d_in[10];
    void* args[] = { (void*)&x, (void*)&Wx0, (void*)&Wx1, (void*)&Wx2, (void*)&Wh,
                     (void*)&bias, (void*)&pi, (void*)&pf, (void*)&po,
                     (void*)&Wd, (void*)&bd, (void*)&out, (void*)&ws };
    hipError_t err = hipLaunchCooperativeKernel((void*)lstm_mix<DEPTH, CP>,
                                                dim3(251), dim3(256), args, 0, stream);
    if (err != hipSuccess)
        hipLaunchKernelGGL((lstm_mix<DEPTH, CP>), dim3(251), dim3(256), 0, stream,
                           x, Wx0, Wx1, Wx2, Wh, bias, pi, pf, po, Wd, bd, out, ws);
}

extern "C" void kernel_launch(void* const* d_in, const int* in_sizes, int n_in,
                              void* d_out, int out_size, void* d_ws, size_t ws_size,
                              hipStream_t stream) {
    float* out = (float*)d_out;
    unsigned* ws = (unsigned*)d_ws;

    auto flagbytes = [](int cp) -> size_t { return (size_t)4 * NF * cp * 32 * 4; };
    auto fragbytes = [](int depth) -> size_t { return (size_t)3 * depth * FR_LS * 4; };

    if (ws_size >= flagbytes(8) + fragbytes(8)) {          // ~4.2 MB
        hipMemsetAsync(d_ws, 0, flagbytes(8), stream);                          // flags = 0
        hipMemsetAsync((char*)d_ws + flagbytes(8), 0xFF, fragbytes(8), stream); // frags: parity-1
        launch_variant<8, 8>(d_in, out, ws, stream);
    } else if (ws_size >= flagbytes(4) + fragbytes(4)) {   // ~2.1 MB
        hipMemsetAsync(d_ws, 0, flagbytes(4), stream);
        hipMemsetAsync((char*)d_ws + flagbytes(4), 0xFF, fragbytes(4), stream);
        launch_variant<4, 4>(d_in, out, ws, stream);
    } else {                                                // ~1.0 MB
        hipMemsetAsync(d_ws, 0, flagbytes(2), stream);
        hipMemsetAsync((char*)d_ws + flagbytes(2), 0xFF, fragbytes(2), stream);
        launch_variant<2, 2>(d_in, out, ws, stream);
    }
}

// Round 3
// 2967.784 us; speedup vs baseline: 1.7698x; 1.7698x over previous
//
#include <hip/hip_runtime.h>
#include <hip/hip_fp16.h>
#include <math.h>

#define B_ 64
#define T_ 700
#define U_ 400
#define NF 704                        // flag slots per array (>= T_ + DEPTH)
#define FR_LS 13312                   // dwords per (layer,slot): 4 bt x 13 kc x 256

typedef _Float16 half8 __attribute__((ext_vector_type(8)));
typedef float float4v __attribute__((ext_vector_type(4)));

union AFrag { unsigned u[4]; half8 h; };

// ---- agent-scope (cross-XCD coherent) helpers ----
__device__ __forceinline__ unsigned agloadu(const unsigned* p) {
    return __hip_atomic_load(p, __ATOMIC_RELAXED, __HIP_MEMORY_SCOPE_AGENT);
}
__device__ __forceinline__ void agstoreu(unsigned* p, unsigned v) {
    __hip_atomic_store(p, v, __ATOMIC_RELAXED, __HIP_MEMORY_SCOPE_AGENT);
}
__device__ __forceinline__ float sig_(float v) {
    return __builtin_amdgcn_rcpf(1.f + __expf(-v));
}
__device__ __forceinline__ float tanh_(float v) {
    return 1.f - 2.f * __builtin_amdgcn_rcpf(__expf(2.f * v) + 1.f);
}
__device__ __forceinline__ void waitflag(const unsigned* f, unsigned target) {
    while (agloadu(f) < target) __builtin_amdgcn_s_sleep(2);
}
__device__ __forceinline__ unsigned f16u(float v) {
    union { _Float16 f; unsigned short s; } cv; cv.f = (_Float16)v; return (unsigned)cv.s;
}

// Parity-tagged own-edge read (R10): DECIMATED probe — 26 active lanes, 2
// sampled dwords per chunk => 26 cachelines/retry (was 64), s_sleep(1)
// cadence. R8/R9 post-mortem: ~1000 waves x 64 scattered cachelines every
// ~270ns ~= 15 TB/s of L3 poll pressure congests the coherence point and
// delays the very stores being polled. Probe has no correctness role; the
// batched pend-masked verify is authoritative. Wrap-parity is ABA-safe
// (same wave observed opposite parity at these addresses DEPTH steps ago).
// EVERY dword in the region (incl. K-pad) is rewritten each step.
__device__ __forceinline__ void pollfrag13(const unsigned* __restrict__ base,
                                           const unsigned par,
                                           AFrag* __restrict__ a, const int lane)
{
    {   // probe: lanes 0..25 sample 2 dwords per chunk; others auto-pass
        const unsigned* pp = base + (lane % 13) * 256 + ((lane * 37) & 255);
        const bool act = lane < 26;
        unsigned v = act ? agloadu(pp) : par;
        while (!__all((int)(((v ^ par) & 1u) == 0u))) {
            __builtin_amdgcn_s_sleep(1);
            if (act) v = agloadu(pp);
        }
    }
    unsigned pend = 0x1FFFu;
    do {
#pragma unroll
        for (int ck = 0; ck < 13; ++ck) if ((pend >> ck) & 1) {
#pragma unroll
            for (int d = 0; d < 4; ++d)
                a[ck].u[d] = agloadu(base + ck * 256 + d * 64 + lane);
        }
#pragma unroll
        for (int ck = 0; ck < 13; ++ck) if ((pend >> ck) & 1) {
            const unsigned m = (a[ck].u[0] ^ par) | (a[ck].u[1] ^ par)
                             | (a[ck].u[2] ^ par) | (a[ck].u[3] ^ par);
            if (__all((int)((m & 1u) == 0u))) pend &= ~(1u << ck);
        }
        if (pend) __builtin_amdgcn_s_sleep(3);
    } while (pend);
}

//  blocks 0..49   : layer 0, 8 units (32 gate-cols), A = h0[t-1]
//  blocks 50..149 : layer 1, 4 units, A = [h0[t] ; h1[t-1]]
//  blocks 150..249: layer 2, 4 units, A = [h1[t] ; h2[t-1]]
//  block 250      : output projection h2[t] @ Wd + bd
//  Own-layer edge: wrap-parity tag in LSB of each packed h dword (direct data poll).
//  Cross-layer input edge + lagged anti-overwrite: replicated flag counters (R5).
//  blk 49/149/249 additionally rewrite the 512 K-pad dwords (u=400..415) of their
//  layer's write slot every step — parity-correct, non-NaN.
template<int DEPTH, int CP>
__global__ void __launch_bounds__(256, 1)
lstm_mix(const float* __restrict__ x,
         const float* __restrict__ Wx0,
         const float* __restrict__ Wx1,
         const float* __restrict__ Wx2,
         const float* __restrict__ Wh,
         const float* __restrict__ bias,
         const float* __restrict__ pi,
         const float* __restrict__ pf,
         const float* __restrict__ po,
         const float* __restrict__ Wd,
         const float* __restrict__ bd,
         float* __restrict__ out,
         unsigned* __restrict__ ws)
{
    __shared__ alignas(16) _Float16 wlds[26 * 512];   // 26.6 KB B-frags [ck][lane][8]
    __shared__ alignas(16) float zlds[4 * 528];       // 8.4 KB per-wave z tiles
    __shared__ float gc[160];                          // gate constants

    const int LW = NF * CP * 32;
    unsigned* F0 = ws;
    unsigned* F1 = F0 + LW;
    unsigned* F2 = F1 + LW;
    unsigned* FO = F2 + LW;
    unsigned* frag0 = ws + (size_t)4 * LW;   // [3][DEPTH][FR_LS], init 0xFF (parity 1)

    const int blk  = blockIdx.x;
    const int tid  = threadIdx.x;
    const int lane = tid & 63;
    const int wv   = tid >> 6;
    const int cpi  = (blk + wv) & (CP - 1);

    int layer, u0;
    if      (blk < 50)  { layer = 0; u0 = blk * 8; }
    else if (blk < 150) { layer = 1; u0 = (blk - 50) * 4; }
    else if (blk < 250) { layer = 2; u0 = (blk - 150) * 4; }
    else                { layer = 3; u0 = 0; }

    const bool padw = (blk == 49) || (blk == 149) || (blk == 249);
    // pad dword addresses (2 per thread): kc=12, q in {2,3}, d in 0..3, b_loc 0..15
    int pad_off[2];
    {
        const int i0 = tid, i1 = tid + 256;
        pad_off[0] = (i0 >> 7) * 3328 + 12 * 256 + (((i0 >> 4) & 3) * 64)
                   + (2 + ((i0 >> 6) & 1)) * 16 + (i0 & 15);
        pad_off[1] = (i1 >> 7) * 3328 + 12 * 256 + (((i1 >> 4) & 3) * 64)
                   + (2 + ((i1 >> 6) & 1)) * 16 + (i1 & 15);
    }

    // ---- one-time: stage weights into LDS in B-fragment order ----
    {
        const float* __restrict__ Wxl = (layer == 1) ? Wx1 : Wx2;
        for (int i = tid; i < 26 * 64; i += 256) {
            const int ln = i & 63, ck = i >> 6;
            const int q = ln >> 4, nn = ln & 15;
            float vals[8];
#pragma unroll
            for (int j = 0; j < 8; ++j) {
                const int kc = ck % 13;
                const int k = kc * 32 + q * 8 + j;
                float v = 0.f;
                if (k < 400) {
                    if (layer == 0) {
                        const int col32 = (ck / 13) * 16 + nn;
                        const int gcol = (col32 >> 3) * U_ + u0 + (col32 & 7);
                        v = Wh[(size_t)k * 1600 + gcol];
                    } else if (layer < 3) {
                        const int gcol = (nn >> 2) * U_ + u0 + (nn & 3);
                        v = (ck >= 13) ? Wh[((size_t)layer * U_ + k) * 1600 + gcol]
                                       : Wxl[(size_t)k * 1600 + gcol];
                    } else {
                        if (ck < 13 && nn < 3) v = Wd[k * 3 + nn];
                    }
                }
                vals[j] = v;
            }
#pragma unroll
            for (int j = 0; j < 8; ++j)
                wlds[ck * 512 + ln * 8 + j] = (_Float16)vals[j];
        }
        if (layer == 0) {
            if (tid < 128) {
                const int col32 = tid >> 2, comp = tid & 3;
                const int gcol = (col32 >> 3) * U_ + u0 + (col32 & 7);
                gc[tid] = (comp == 0) ? bias[gcol] : Wx0[(size_t)(comp - 1) * 1600 + gcol];
            } else if (tid < 152) {
                const int idx = tid - 128, ul = idx / 3, j = idx - ul * 3;
                const float* pp = (j == 0) ? pi : (j == 1) ? pf : po;
                gc[tid] = pp[u0 + ul];
            }
        } else if (layer < 3) {
            if (tid < 16) {
                gc[tid] = bias[layer * 1600 + (tid >> 2) * U_ + u0 + (tid & 3)];
            } else if (tid < 28) {
                const int idx = tid - 16, ul = idx / 3, j = idx - ul * 3;
                const float* pp = (j == 0) ? pi : (j == 1) ? pf : po;
                gc[tid] = pp[layer * U_ + u0 + ul];
            }
        } else {
            if (tid < 3) gc[tid] = bd[tid];
        }
    }
    __syncthreads();

    const int wvz   = wv * 528;
    const int b_loc = lane & 15;
    const int quad  = lane >> 4;
    float cst[2] = {0.f, 0.f};

    for (int t = 0; t < T_; ++t) {
        const int sw = t % DEPTH;
        const int sr = (t + DEPTH - 1) % DEPTH;
        const unsigned pI = (unsigned)((t / DEPTH) & 1);          // parity written at t
        const unsigned pO = (unsigned)(((t - 1) / DEPTH) & 1);    // parity of h[t-1] slot

        // x prefetch (L0), independent of sync
        float x0, x1, x2;
        if (layer == 0) {
            const size_t xb = (size_t)(wv * 16 + b_loc) * T_ + t;
            x0 = x[xb * 3 + 0]; x1 = x[xb * 3 + 1]; x2 = x[xb * 3 + 2];
        }

        // ---- input-edge flag waits + lagged anti-overwrite (R5 scheme) ----
        if (lane == 0) {
            if (layer == 0) {
                if (wv == 0 && t >= DEPTH) waitflag(F1 + ((t - DEPTH) * CP + cpi) * 32, 100);
            } else if (layer == 1) {
                waitflag(F0 + (t * CP + cpi) * 32, 50);
                if (wv == 0 && t >= DEPTH) waitflag(F2 + ((t - DEPTH) * CP + cpi) * 32, 100);
            } else if (layer == 2) {
                waitflag(F1 + (t * CP + cpi) * 32, 100);
                if (wv == 0 && t >= DEPTH) waitflag(FO + ((t - DEPTH) * CP + cpi) * 32, 1);
            } else {
                waitflag(F2 + (t * CP + cpi) * 32, 100);
            }
        }
        asm volatile("" ::: "memory");

        // input-edge loads (in flight while the own-edge poll spins)
        AFrag ainp[13];
        if (layer == 1 || layer == 2) {
            const unsigned* frI = frag0 + (size_t)((layer - 1) * DEPTH + sw) * FR_LS + wv * 3328;
#pragma unroll
            for (int kc = 0; kc < 13; ++kc)
#pragma unroll
                for (int d = 0; d < 4; ++d)
                    ainp[kc].u[d] = agloadu(frI + kc * 256 + d * 64 + lane);
        }

        // own-edge: parity-tagged data poll (the critical cycle)
        AFrag aown[13];
        if (layer == 3) {
            const unsigned* frI = frag0 + (size_t)(2 * DEPTH + sw) * FR_LS + wv * 3328;
#pragma unroll
            for (int kc = 0; kc < 13; ++kc)
#pragma unroll
                for (int d = 0; d < 4; ++d)
                    aown[kc].u[d] = agloadu(frI + kc * 256 + d * 64 + lane);
        } else if (t >= 1) {
            const unsigned* frO = frag0 + (size_t)(layer * DEPTH + sr) * FR_LS + wv * 3328;
            pollfrag13(frO, pO, aown, lane);
        } else {
#pragma unroll
            for (int kc = 0; kc < 13; ++kc)
#pragma unroll
                for (int d = 0; d < 4; ++d) aown[kc].u[d] = 0u;
        }
        asm volatile("" ::: "memory");

        // ---- MFMA ----
        if (layer == 0) {
            float4v acc0 = {0.f, 0.f, 0.f, 0.f}, acc1 = {0.f, 0.f, 0.f, 0.f};
#pragma unroll
            for (int kc = 0; kc < 13; ++kc) {
                const half8 w0 = *(const half8*)&wlds[kc * 512 + lane * 8];
                const half8 w1 = *(const half8*)&wlds[(13 + kc) * 512 + lane * 8];
                acc0 = __builtin_amdgcn_mfma_f32_16x16x32_f16(aown[kc].h, w0, acc0, 0, 0, 0);
                acc1 = __builtin_amdgcn_mfma_f32_16x16x32_f16(aown[kc].h, w1, acc1, 0, 0, 0);
            }
#pragma unroll
            for (int r = 0; r < 4; ++r) {
                zlds[wvz + (quad * 4 + r) * 33 + b_loc] = acc0[r];
                zlds[wvz + (quad * 4 + r) * 33 + 16 + b_loc] = acc1[r];
            }
        } else if (layer < 3) {
            float4v acc = {0.f, 0.f, 0.f, 0.f};
#pragma unroll
            for (int kc = 0; kc < 13; ++kc) {
                const half8 wA = *(const half8*)&wlds[kc * 512 + lane * 8];          // Wx part
                const half8 wB = *(const half8*)&wlds[(13 + kc) * 512 + lane * 8];   // Wh part
                acc = __builtin_amdgcn_mfma_f32_16x16x32_f16(ainp[kc].h, wA, acc, 0, 0, 0);
                acc = __builtin_amdgcn_mfma_f32_16x16x32_f16(aown[kc].h, wB, acc, 0, 0, 0);
            }
#pragma unroll
            for (int r = 0; r < 4; ++r)
                zlds[wvz + (quad * 4 + r) * 33 + b_loc] = acc[r];
        } else {
            float4v acc = {0.f, 0.f, 0.f, 0.f};
#pragma unroll
            for (int kc = 0; kc < 13; ++kc) {
                const half8 w0 = *(const half8*)&wlds[kc * 512 + lane * 8];
                acc = __builtin_amdgcn_mfma_f32_16x16x32_f16(aown[kc].h, w0, acc, 0, 0, 0);
            }
            if (b_loc < 3) {
#pragma unroll
                for (int r = 0; r < 4; ++r)
                    out[((size_t)(wv * 16 + quad * 4 + r) * T_ + t) * 3 + b_loc] = acc[r] + gc[b_loc];
            }
        }
        __syncthreads();   // zlds ready; also orders the lagged waits before stores

        // ---- K-pad rewrite (designated block per layer): parity-correct, non-NaN ----
        if (padw) {
            unsigned* fr_dst = frag0 + (size_t)(layer * DEPTH + sw) * FR_LS;
            agstoreu(fr_dst + pad_off[0], pI);
            agstoreu(fr_dst + pad_off[1], pI);
        }

        // ---- gates (fp32) + parity-tagged h store in A-fragment layout ----
        if (layer == 0) {
            unsigned* fr_dst = frag0 + (size_t)(0 * DEPTH + sw) * FR_LS + wv * 3328;
#pragma unroll
            for (int q = 0; q < 2; ++q) {
                const int ul = q * 4 + quad;
                const int ug = u0 + ul;
                float z[4];
#pragma unroll
                for (int g = 0; g < 4; ++g) {
                    const int gb = (g * 8 + ul) * 4;
                    z[g] = zlds[wvz + b_loc * 33 + g * 8 + ul]
                         + gc[gb + 0] + x0 * gc[gb + 1] + x1 * gc[gb + 2] + x2 * gc[gb + 3];
                }
                const float cp = cst[q];
                const float ig = sig_(z[0] + gc[128 + ul * 3 + 0] * cp);
                const float fg = sig_(z[1] + gc[128 + ul * 3 + 1] * cp);
                const float cn = fg * cp + ig * tanh_(z[2]);
                const float og = sig_(z[3] + gc[128 + ul * 3 + 2] * cn);
                cst[q] = cn;
                const float hv = og * tanh_(cn);
                const float pv = __shfl_xor(hv, 16, 64);
                if ((quad & 1) == 0) {
                    const unsigned pw_ = ((f16u(hv) & ~1u) | pI) | (f16u(pv) << 16);
                    const int u = ug;                    // even
                    agstoreu(fr_dst + (u >> 5) * 256 + ((u & 7) >> 1) * 64
                                    + ((u >> 3) & 3) * 16 + b_loc, pw_);
                }
            }
        } else if (layer < 3) {
            unsigned* fr_dst = frag0 + (size_t)(layer * DEPTH + sw) * FR_LS + wv * 3328;
            const int ul = quad;
            float z[4];
#pragma unroll
            for (int g = 0; g < 4; ++g)
                z[g] = zlds[wvz + b_loc * 33 + g * 4 + ul] + gc[g * 4 + ul];
            const float cp = cst[0];
            const float ig = sig_(z[0] + gc[16 + ul * 3 + 0] * cp);
            const float fg = sig_(z[1] + gc[16 + ul * 3 + 1] * cp);
            const float cn = fg * cp + ig * tanh_(z[2]);
            const float og = sig_(z[3] + gc[16 + ul * 3 + 2] * cn);
            cst[0] = cn;
            const float hv = og * tanh_(cn);
            const float pv = __shfl_xor(hv, 16, 64);
            if ((ul & 1) == 0) {
                const unsigned pw_ = ((f16u(hv) & ~1u) | pI) | (f16u(pv) << 16);
                const int u = u0 + ul;                   // even
                agstoreu(fr_dst + (u >> 5) * 256 + ((u & 7) >> 1) * 64
                                + ((u >> 3) & 3) * 16 + b_loc, pw_);
            }
        }

        // ---- publish flags (input edge + anti-overwrite consumers only) ----
        asm volatile("s_waitcnt vmcnt(0)" ::: "memory");
        __syncthreads();
        if (tid < CP) {
            unsigned* f = (layer == 0) ? F0 : (layer == 1) ? F1
                        : (layer == 2) ? F2 : FO;
            __hip_atomic_fetch_add(f + (t * CP + tid) * 32, 1u,
                                   __ATOMIC_RELAXED, __HIP_MEMORY_SCOPE_AGENT);
        }
    }
}

template<int DEPTH, int CP>
static void launch_variant(void* const* d_in, float* out, unsigned* ws, hipStream_t stream) {
    const float* x    = (const float*)d_in[0];
    const float* Wx0  = (const float*)d_in[1];
    const float* Wx1  = (const float*)d_in[2];
    const float* Wx2  = (const float*)d_in[3];
    const float* Wh   = (const float*)d_in[4];
    const float* bias = (const float*)d_in[5];
    const float* pi   = (const float*)d_in[6];
    const float* pf   = (const float*)d_in[7];
    const float* po   = (const float*)d_in[8];
    const float* Wd   = (const float*)d_in[9];
    const float* bd   = (const float*)d_in[10];
    void* args[] = { (void*)&x, (void*)&Wx0, (void*)&Wx1, (void*)&Wx2, (void*)&Wh,
                     (void*)&bias, (void*)&pi, (void*)&pf, (void*)&po,
                     (void*)&Wd, (void*)&bd, (void*)&out, (void*)&ws };
    hipError_t err = hipLaunchCooperativeKernel((void*)lstm_mix<DEPTH, CP>,
                                                dim3(251), dim3(256), args, 0, stream);
    if (err != hipSuccess)
        hipLaunchKernelGGL((lstm_mix<DEPTH, CP>), dim3(251), dim3(256), 0, stream,
                           x, Wx0, Wx1, Wx2, Wh, bias, pi, pf, po, Wd, bd, out, ws);
}

extern "C" void kernel_launch(void* const* d_in, const int* in_sizes, int n_in,
                              void* d_out, int out_size, void* d_ws, size_t ws_size,
                              hipStream_t stream) {
    float* out = (float*)d_out;
    unsigned* ws = (unsigned*)d_ws;

    auto flagbytes = [](int cp) -> size_t { return (size_t)4 * NF * cp * 32 * 4; };
    auto fragbytes = [](int depth) -> size_t { return (size_t)3 * depth * FR_LS * 4; };

    if (ws_size >= flagbytes(8) + fragbytes(8)) {          // ~4.2 MB
        hipMemsetAsync(d_ws, 0, flagbytes(8), stream);                          // flags = 0
        hipMemsetAsync((char*)d_ws + flagbytes(8), 0xFF, fragbytes(8), stream); // frags: parity-1
        launch_variant<8, 8>(d_in, out, ws, stream);
    } else if (ws_size >= flagbytes(4) + fragbytes(4)) {   // ~2.1 MB
        hipMemsetAsync(d_ws, 0, flagbytes(4), stream);
        hipMemsetAsync((char*)d_ws + flagbytes(4), 0xFF, fragbytes(4), stream);
        launch_variant<4, 4>(d_in, out, ws, stream);
    } else {                                                // ~1.0 MB
        hipMemsetAsync(d_ws, 0, flagbytes(2), stream);
        hipMemsetAsync((char*)d_ws + flagbytes(2), 0xFF, fragbytes(2), stream);
        launch_variant<2, 2>(d_in, out, ws, stream);
    }
}

// Round 4
// 2943.041 us; speedup vs baseline: 1.7847x; 1.0084x over previous
//
#include <hip/hip_runtime.h>
#include <hip/hip_fp16.h>
#include <math.h>

#define B_ 64
#define T_ 700
#define U_ 400
#define NF 704                        // flag slots per array (>= T_ + DEPTH)
#define FR_LS 13312                   // dwords per (layer,slot): 4 bt x 13 kc x 256

typedef _Float16 half8 __attribute__((ext_vector_type(8)));
typedef float float4v __attribute__((ext_vector_type(4)));

union AFrag { unsigned u[4]; half8 h; };

// ---- agent-scope (cross-XCD coherent) helpers ----
__device__ __forceinline__ unsigned agloadu(const unsigned* p) {
    return __hip_atomic_load(p, __ATOMIC_RELAXED, __HIP_MEMORY_SCOPE_AGENT);
}
__device__ __forceinline__ void agstoreu(unsigned* p, unsigned v) {
    __hip_atomic_store(p, v, __ATOMIC_RELAXED, __HIP_MEMORY_SCOPE_AGENT);
}
__device__ __forceinline__ float sig_(float v) {
    return __builtin_amdgcn_rcpf(1.f + __expf(-v));
}
__device__ __forceinline__ float tanh_(float v) {
    return 1.f - 2.f * __builtin_amdgcn_rcpf(__expf(2.f * v) + 1.f);
}
__device__ __forceinline__ void waitflag(const unsigned* f, unsigned target) {
    while (agloadu(f) < target) __builtin_amdgcn_s_sleep(2);
}
__device__ __forceinline__ unsigned f16u(float v) {
    union { _Float16 f; unsigned short s; } cv; cv.f = (_Float16)v; return (unsigned)cv.s;
}

// Parity-tagged own-edge read (R7 form, restored verbatim — R10's decimation
// fired the probe early and pushed waits into expensive verify retries).
// Sloppy low-volume probe (1 dword/lane, sleep-backed), then batched verify
// over 13 chunks x 4 dwords. Verify is authoritative; wrap-parity is ABA-safe
// (same wave observed opposite parity at these addresses DEPTH steps ago).
// EVERY dword in the region (incl. K-pad) is rewritten each step.
__device__ __forceinline__ void pollfrag13(const unsigned* __restrict__ base,
                                           const unsigned par,
                                           AFrag* __restrict__ a, const int lane)
{
    {   // probe: 1 dword/lane spread across all 13 chunks (no correctness role)
        const unsigned* pp = base + (lane % 13) * 256 + ((lane * 37) & 255);
        while (!__all((int)(((agloadu(pp) ^ par) & 1u) == 0u)))
            __builtin_amdgcn_s_sleep(3);
    }
    unsigned pend = 0x1FFFu;
    do {
#pragma unroll
        for (int ck = 0; ck < 13; ++ck) if ((pend >> ck) & 1) {
#pragma unroll
            for (int d = 0; d < 4; ++d)
                a[ck].u[d] = agloadu(base + ck * 256 + d * 64 + lane);
        }
#pragma unroll
        for (int ck = 0; ck < 13; ++ck) if ((pend >> ck) & 1) {
            const unsigned m = (a[ck].u[0] ^ par) | (a[ck].u[1] ^ par)
                             | (a[ck].u[2] ^ par) | (a[ck].u[3] ^ par);
            if (__all((int)((m & 1u) == 0u))) pend &= ~(1u << ck);
        }
        if (pend) __builtin_amdgcn_s_sleep(3);
    } while (pend);
}

// R11: pend-masked parity VERIFY without a probe — correctness backstop for
// flag-gated cross-layer edges now that the producer-side vmcnt(0) store
// drain is removed. The flag-wait (1 hot cacheline — the cheap mechanism
// R8/R9 wrongly replaced) still does the WAITING; data stores were issued
// well before the flag became visible, so the first check almost always
// passes (pure VALU). Retries are rare, bounded by store-flight skew.
__device__ __forceinline__ void verifyfrag13(const unsigned* __restrict__ base,
                                             const unsigned par,
                                             AFrag* __restrict__ a, const int lane)
{
    unsigned pend = 0x1FFFu;
#pragma unroll
    for (int ck = 0; ck < 13; ++ck) {
        const unsigned m = (a[ck].u[0] ^ par) | (a[ck].u[1] ^ par)
                         | (a[ck].u[2] ^ par) | (a[ck].u[3] ^ par);
        if (__all((int)((m & 1u) == 0u))) pend &= ~(1u << ck);
    }
    while (pend) {
        __builtin_amdgcn_s_sleep(2);
#pragma unroll
        for (int ck = 0; ck < 13; ++ck) if ((pend >> ck) & 1) {
#pragma unroll
            for (int d = 0; d < 4; ++d)
                a[ck].u[d] = agloadu(base + ck * 256 + d * 64 + lane);
        }
#pragma unroll
        for (int ck = 0; ck < 13; ++ck) if ((pend >> ck) & 1) {
            const unsigned m = (a[ck].u[0] ^ par) | (a[ck].u[1] ^ par)
                             | (a[ck].u[2] ^ par) | (a[ck].u[3] ^ par);
            if (__all((int)((m & 1u) == 0u))) pend &= ~(1u << ck);
        }
    }
}

//  blocks 0..49   : layer 0, 8 units (32 gate-cols), A = h0[t-1]
//  blocks 50..149 : layer 1, 4 units, A = [h0[t] ; h1[t-1]]
//  blocks 150..249: layer 2, 4 units, A = [h1[t] ; h2[t-1]]
//  block 250      : output projection h2[t] @ Wd + bd
//  R11 sync scheme (= R7 waits + drain removal):
//   - Own-layer edge: wrap-parity data poll (probe + verify), as in R7.
//   - Cross-layer data-ready + lagged anti-overwrite: flag counters, as in R7.
//   - NEW: no s_waitcnt vmcnt(0) before the flag publish. Flag-gated readers
//     parity-VERIFY their loaded data instead (verifyfrag13); consumption
//     markers never needed release ordering (loads consumed by MFMA before
//     barrier2). Same-lane same-address store ordering keeps epochs ABA-safe.
//  blk 49/149/249 additionally rewrite the 512 K-pad dwords (u=400..415) of
//  their layer's write slot every step — parity-correct, non-NaN.
template<int DEPTH, int CP>
__global__ void __launch_bounds__(256, 1)
lstm_mix(const float* __restrict__ x,
         const float* __restrict__ Wx0,
         const float* __restrict__ Wx1,
         const float* __restrict__ Wx2,
         const float* __restrict__ Wh,
         const float* __restrict__ bias,
         const float* __restrict__ pi,
         const float* __restrict__ pf,
         const float* __restrict__ po,
         const float* __restrict__ Wd,
         const float* __restrict__ bd,
         float* __restrict__ out,
         unsigned* __restrict__ ws)
{
    __shared__ alignas(16) _Float16 wlds[26 * 512];   // 26.6 KB B-frags [ck][lane][8]
    __shared__ alignas(16) float zlds[4 * 528];       // 8.4 KB per-wave z tiles
    __shared__ float gc[160];                          // gate constants

    const int LW = NF * CP * 32;
    unsigned* F0 = ws;
    unsigned* F1 = F0 + LW;
    unsigned* F2 = F1 + LW;
    unsigned* FO = F2 + LW;
    unsigned* frag0 = ws + (size_t)4 * LW;   // [3][DEPTH][FR_LS], init 0xFF (parity 1)

    const int blk  = blockIdx.x;
    const int tid  = threadIdx.x;
    const int lane = tid & 63;
    const int wv   = tid >> 6;
    const int cpi  = (blk + wv) & (CP - 1);

    int layer, u0;
    if      (blk < 50)  { layer = 0; u0 = blk * 8; }
    else if (blk < 150) { layer = 1; u0 = (blk - 50) * 4; }
    else if (blk < 250) { layer = 2; u0 = (blk - 150) * 4; }
    else                { layer = 3; u0 = 0; }

    const bool padw = (blk == 49) || (blk == 149) || (blk == 249);
    // pad dword addresses (2 per thread): kc=12, q in {2,3}, d in 0..3, b_loc 0..15
    int pad_off[2];
    {
        const int i0 = tid, i1 = tid + 256;
        pad_off[0] = (i0 >> 7) * 3328 + 12 * 256 + (((i0 >> 4) & 3) * 64)
                   + (2 + ((i0 >> 6) & 1)) * 16 + (i0 & 15);
        pad_off[1] = (i1 >> 7) * 3328 + 12 * 256 + (((i1 >> 4) & 3) * 64)
                   + (2 + ((i1 >> 6) & 1)) * 16 + (i1 & 15);
    }

    // ---- one-time: stage weights into LDS in B-fragment order ----
    {
        const float* __restrict__ Wxl = (layer == 1) ? Wx1 : Wx2;
        for (int i = tid; i < 26 * 64; i += 256) {
            const int ln = i & 63, ck = i >> 6;
            const int q = ln >> 4, nn = ln & 15;
            float vals[8];
#pragma unroll
            for (int j = 0; j < 8; ++j) {
                const int kc = ck % 13;
                const int k = kc * 32 + q * 8 + j;
                float v = 0.f;
                if (k < 400) {
                    if (layer == 0) {
                        const int col32 = (ck / 13) * 16 + nn;
                        const int gcol = (col32 >> 3) * U_ + u0 + (col32 & 7);
                        v = Wh[(size_t)k * 1600 + gcol];
                    } else if (layer < 3) {
                        const int gcol = (nn >> 2) * U_ + u0 + (nn & 3);
                        v = (ck >= 13) ? Wh[((size_t)layer * U_ + k) * 1600 + gcol]
                                       : Wxl[(size_t)k * 1600 + gcol];
                    } else {
                        if (ck < 13 && nn < 3) v = Wd[k * 3 + nn];
                    }
                }
                vals[j] = v;
            }
#pragma unroll
            for (int j = 0; j < 8; ++j)
                wlds[ck * 512 + ln * 8 + j] = (_Float16)vals[j];
        }
        if (layer == 0) {
            if (tid < 128) {
                const int col32 = tid >> 2, comp = tid & 3;
                const int gcol = (col32 >> 3) * U_ + u0 + (col32 & 7);
                gc[tid] = (comp == 0) ? bias[gcol] : Wx0[(size_t)(comp - 1) * 1600 + gcol];
            } else if (tid < 152) {
                const int idx = tid - 128, ul = idx / 3, j = idx - ul * 3;
                const float* pp = (j == 0) ? pi : (j == 1) ? pf : po;
                gc[tid] = pp[u0 + ul];
            }
        } else if (layer < 3) {
            if (tid < 16) {
                gc[tid] = bias[layer * 1600 + (tid >> 2) * U_ + u0 + (tid & 3)];
            } else if (tid < 28) {
                const int idx = tid - 16, ul = idx / 3, j = idx - ul * 3;
                const float* pp = (j == 0) ? pi : (j == 1) ? pf : po;
                gc[tid] = pp[layer * U_ + u0 + ul];
            }
        } else {
            if (tid < 3) gc[tid] = bd[tid];
        }
    }
    __syncthreads();

    const int wvz   = wv * 528;
    const int b_loc = lane & 15;
    const int quad  = lane >> 4;
    float cst[2] = {0.f, 0.f};

    for (int t = 0; t < T_; ++t) {
        const int sw = t % DEPTH;
        const int sr = (t + DEPTH - 1) % DEPTH;
        const unsigned pI = (unsigned)((t / DEPTH) & 1);          // parity written at t
        const unsigned pO = (unsigned)(((t - 1) / DEPTH) & 1);    // parity of h[t-1] slot

        // x prefetch (L0), independent of sync
        float x0, x1, x2;
        if (layer == 0) {
            const size_t xb = (size_t)(wv * 16 + b_loc) * T_ + t;
            x0 = x[xb * 3 + 0]; x1 = x[xb * 3 + 1]; x2 = x[xb * 3 + 2];
        }

        // ---- input-edge flag waits + lagged anti-overwrite (R5 scheme) ----
        if (lane == 0) {
            if (layer == 0) {
                if (wv == 0 && t >= DEPTH) waitflag(F1 + ((t - DEPTH) * CP + cpi) * 32, 100);
            } else if (layer == 1) {
                waitflag(F0 + (t * CP + cpi) * 32, 50);
                if (wv == 0 && t >= DEPTH) waitflag(F2 + ((t - DEPTH) * CP + cpi) * 32, 100);
            } else if (layer == 2) {
                waitflag(F1 + (t * CP + cpi) * 32, 100);
                if (wv == 0 && t >= DEPTH) waitflag(FO + ((t - DEPTH) * CP + cpi) * 32, 1);
            } else {
                waitflag(F2 + (t * CP + cpi) * 32, 100);
            }
        }
        asm volatile("" ::: "memory");

        // input-edge loads (in flight while the own-edge poll spins)
        AFrag ainp[13];
        const unsigned* frInp = nullptr;
        if (layer == 1 || layer == 2) {
            frInp = frag0 + (size_t)((layer - 1) * DEPTH + sw) * FR_LS + wv * 3328;
#pragma unroll
            for (int kc = 0; kc < 13; ++kc)
#pragma unroll
                for (int d = 0; d < 4; ++d)
                    ainp[kc].u[d] = agloadu(frInp + kc * 256 + d * 64 + lane);
        }

        // own-edge: parity-tagged data poll (the critical cycle)
        AFrag aown[13];
        if (layer == 3) {
            const unsigned* frI = frag0 + (size_t)(2 * DEPTH + sw) * FR_LS + wv * 3328;
#pragma unroll
            for (int kc = 0; kc < 13; ++kc)
#pragma unroll
                for (int d = 0; d < 4; ++d)
                    aown[kc].u[d] = agloadu(frI + kc * 256 + d * 64 + lane);
            verifyfrag13(frI, pI, aown, lane);        // flag may outrun data (no drain)
        } else if (t >= 1) {
            const unsigned* frO = frag0 + (size_t)(layer * DEPTH + sr) * FR_LS + wv * 3328;
            pollfrag13(frO, pO, aown, lane);
        } else {
#pragma unroll
            for (int kc = 0; kc < 13; ++kc)
#pragma unroll
                for (int d = 0; d < 4; ++d) aown[kc].u[d] = 0u;
        }
        // cross-layer input backstop: verify parity of the flag-gated loads
        if (layer == 1 || layer == 2)
            verifyfrag13(frInp, pI, ainp, lane);
        asm volatile("" ::: "memory");

        // ---- MFMA ----
        if (layer == 0) {
            float4v acc0 = {0.f, 0.f, 0.f, 0.f}, acc1 = {0.f, 0.f, 0.f, 0.f};
#pragma unroll
            for (int kc = 0; kc < 13; ++kc) {
                const half8 w0 = *(const half8*)&wlds[kc * 512 + lane * 8];
                const half8 w1 = *(const half8*)&wlds[(13 + kc) * 512 + lane * 8];
                acc0 = __builtin_amdgcn_mfma_f32_16x16x32_f16(aown[kc].h, w0, acc0, 0, 0, 0);
                acc1 = __builtin_amdgcn_mfma_f32_16x16x32_f16(aown[kc].h, w1, acc1, 0, 0, 0);
            }
#pragma unroll
            for (int r = 0; r < 4; ++r) {
                zlds[wvz + (quad * 4 + r) * 33 + b_loc] = acc0[r];
                zlds[wvz + (quad * 4 + r) * 33 + 16 + b_loc] = acc1[r];
            }
        } else if (layer < 3) {
            float4v acc = {0.f, 0.f, 0.f, 0.f};
#pragma unroll
            for (int kc = 0; kc < 13; ++kc) {
                const half8 wA = *(const half8*)&wlds[kc * 512 + lane * 8];          // Wx part
                const half8 wB = *(const half8*)&wlds[(13 + kc) * 512 + lane * 8];   // Wh part
                acc = __builtin_amdgcn_mfma_f32_16x16x32_f16(ainp[kc].h, wA, acc, 0, 0, 0);
                acc = __builtin_amdgcn_mfma_f32_16x16x32_f16(aown[kc].h, wB, acc, 0, 0, 0);
            }
#pragma unroll
            for (int r = 0; r < 4; ++r)
                zlds[wvz + (quad * 4 + r) * 33 + b_loc] = acc[r];
        } else {
            float4v acc = {0.f, 0.f, 0.f, 0.f};
#pragma unroll
            for (int kc = 0; kc < 13; ++kc) {
                const half8 w0 = *(const half8*)&wlds[kc * 512 + lane * 8];
                acc = __builtin_amdgcn_mfma_f32_16x16x32_f16(aown[kc].h, w0, acc, 0, 0, 0);
            }
            if (b_loc < 3) {
#pragma unroll
                for (int r = 0; r < 4; ++r)
                    out[((size_t)(wv * 16 + quad * 4 + r) * T_ + t) * 3 + b_loc] = acc[r] + gc[b_loc];
            }
        }
        __syncthreads();   // zlds ready; also orders the lagged waits before stores

        // ---- K-pad rewrite (designated block per layer): parity-correct, non-NaN ----
        if (padw) {
            unsigned* fr_dst = frag0 + (size_t)(layer * DEPTH + sw) * FR_LS;
            agstoreu(fr_dst + pad_off[0], pI);
            agstoreu(fr_dst + pad_off[1], pI);
        }

        // ---- gates (fp32) + parity-tagged h store in A-fragment layout ----
        if (layer == 0) {
            unsigned* fr_dst = frag0 + (size_t)(0 * DEPTH + sw) * FR_LS + wv * 3328;
#pragma unroll
            for (int q = 0; q < 2; ++q) {
                const int ul = q * 4 + quad;
                const int ug = u0 + ul;
                float z[4];
#pragma unroll
                for (int g = 0; g < 4; ++g) {
                    const int gb = (g * 8 + ul) * 4;
                    z[g] = zlds[wvz + b_loc * 33 + g * 8 + ul]
                         + gc[gb + 0] + x0 * gc[gb + 1] + x1 * gc[gb + 2] + x2 * gc[gb + 3];
                }
                const float cp = cst[q];
                const float ig = sig_(z[0] + gc[128 + ul * 3 + 0] * cp);
                const float fg = sig_(z[1] + gc[128 + ul * 3 + 1] * cp);
                const float cn = fg * cp + ig * tanh_(z[2]);
                const float og = sig_(z[3] + gc[128 + ul * 3 + 2] * cn);
                cst[q] = cn;
                const float hv = og * tanh_(cn);
                const float pv = __shfl_xor(hv, 16, 64);
                if ((quad & 1) == 0) {
                    const unsigned pw_ = ((f16u(hv) & ~1u) | pI) | (f16u(pv) << 16);
                    const int u = ug;                    // even
                    agstoreu(fr_dst + (u >> 5) * 256 + ((u & 7) >> 1) * 64
                                    + ((u >> 3) & 3) * 16 + b_loc, pw_);
                }
            }
        } else if (layer < 3) {
            unsigned* fr_dst = frag0 + (size_t)(layer * DEPTH + sw) * FR_LS + wv * 3328;
            const int ul = quad;
            float z[4];
#pragma unroll
            for (int g = 0; g < 4; ++g)
                z[g] = zlds[wvz + b_loc * 33 + g * 4 + ul] + gc[g * 4 + ul];
            const float cp = cst[0];
            const float ig = sig_(z[0] + gc[16 + ul * 3 + 0] * cp);
            const float fg = sig_(z[1] + gc[16 + ul * 3 + 1] * cp);
            const float cn = fg * cp + ig * tanh_(z[2]);
            const float og = sig_(z[3] + gc[16 + ul * 3 + 2] * cn);
            cst[0] = cn;
            const float hv = og * tanh_(cn);
            const float pv = __shfl_xor(hv, 16, 64);
            if ((ul & 1) == 0) {
                const unsigned pw_ = ((f16u(hv) & ~1u) | pI) | (f16u(pv) << 16);
                const int u = u0 + ul;                   // even
                agstoreu(fr_dst + (u >> 5) * 256 + ((u & 7) >> 1) * 64
                                + ((u >> 3) & 3) * 16 + b_loc, pw_);
            }
        }

        // ---- publish flags: NO vmcnt(0) drain (R11). Readers parity-verify
        //      data; consumption markers were consumed pre-barrier. ----
        __syncthreads();
        if (tid < CP) {
            unsigned* f = (layer == 0) ? F0 : (layer == 1) ? F1
                        : (layer == 2) ? F2 : FO;
            __hip_atomic_fetch_add(f + (t * CP + tid) * 32, 1u,
                                   __ATOMIC_RELAXED, __HIP_MEMORY_SCOPE_AGENT);
        }
    }
}

template<int DEPTH, int CP>
static void launch_variant(void* const* d_in, float* out, unsigned* ws, hipStream_t stream) {
    const float* x    = (const float*)d_in[0];
    const float* Wx0  = (const float*)d_in[1];
    const float* Wx1  = (const float*)d_in[2];
    const float* Wx2  = (const float*)d_in[3];
    const float* Wh   = (const float*)d_in[4];
    const float* bias = (const float*)d_in[5];
    const float* pi   = (const float*)d_in[6];
    const float* pf   = (const float*)d_in[7];
    const float* po   = (const float*)d_in[8];
    const float* Wd   = (const float*)d_in[9];
    const float* bd   = (const float*)d_in[10];
    void* args[] = { (void*)&x, (void*)&Wx0, (void*)&Wx1, (void*)&Wx2, (void*)&Wh,
                     (void*)&bias, (void*)&pi, (void*)&pf, (void*)&po,
                     (void*)&Wd, (void*)&bd, (void*)&out, (void*)&ws };
    hipError_t err = hipLaunchCooperativeKernel((void*)lstm_mix<DEPTH, CP>,
                                                dim3(251), dim3(256), args, 0, stream);
    if (err != hipSuccess)
        hipLaunchKernelGGL((lstm_mix<DEPTH, CP>), dim3(251), dim3(256), 0, stream,
                           x, Wx0, Wx1, Wx2, Wh, bias, pi, pf, po, Wd, bd, out, ws);
}

extern "C" void kernel_launch(void* const* d_in, const int* in_sizes, int n_in,
                              void* d_out, int out_size, void* d_ws, size_t ws_size,
                              hipStream_t stream) {
    float* out = (float*)d_out;
    unsigned* ws = (unsigned*)d_ws;

    auto flagbytes = [](int cp) -> size_t { return (size_t)4 * NF * cp * 32 * 4; };
    auto fragbytes = [](int depth) -> size_t { return (size_t)3 * depth * FR_LS * 4; };

    if (ws_size >= flagbytes(8) + fragbytes(8)) {          // ~4.2 MB
        hipMemsetAsync(d_ws, 0, flagbytes(8), stream);                          // flags = 0
        hipMemsetAsync((char*)d_ws + flagbytes(8), 0xFF, fragbytes(8), stream); // frags: parity-1
        launch_variant<8, 8>(d_in, out, ws, stream);
    } else if (ws_size >= flagbytes(4) + fragbytes(4)) {   // ~2.1 MB
        hipMemsetAsync(d_ws, 0, flagbytes(4), stream);
        hipMemsetAsync((char*)d_ws + flagbytes(4), 0xFF, fragbytes(4), stream);
        launch_variant<4, 4>(d_in, out, ws, stream);
    } else {                                                // ~1.0 MB
        hipMemsetAsync(d_ws, 0, flagbytes(2), stream);
        hipMemsetAsync((char*)d_ws + flagbytes(2), 0xFF, fragbytes(2), stream);
        launch_variant<2, 2>(d_in, out, ws, stream);
    }
}